// Round 9
// baseline (83.132 us; speedup 1.0000x reference)
//
#include <hip/hip_runtime.h>
#include <hip/hip_bf16.h>
#include <math.h>

// Problem constants (from reference setup_inputs)
constexpr int B = 4, S = 10, N = 2048, D = 128;

constexpr int THREADS = 512;          // 8 waves
constexpr int QBLK    = 256;          // queries per block (8 waves x 32 rows)
constexpr int NQG     = N / QBLK;     // 8 query groups
constexpr int HPTS    = 1024;         // db points staged per half
constexpr int HT      = HPTS / 32;    // 32 g-tiles per half
constexpr int CHAM_BLOCKS = B * S * 2 * NQG;   // 640
constexpr int TEMP_ELEMS = B * (S - 1) * N;    // 73728
constexpr int TEMP_BLOCKS = 16;
constexpr int TEMP_PER_BLOCK = TEMP_ELEMS / TEMP_BLOCKS;  // 4608 = 9*512
constexpr int KL_ELEMS = B * S * D;            // 5120 = 10*512
constexpr int K1_GRID  = CHAM_BLOCKS + TEMP_BLOCKS + 1;  // 657

// ws layout (floats): [0..640) chamfer block sums; [640..656) temporal; 656 kl
constexpr size_t WS_CHSUM = 0;
constexpr size_t WS_TPART = CHAM_BLOCKS;
constexpr size_t WS_KL    = WS_TPART + TEMP_BLOCKS;

typedef __attribute__((ext_vector_type(8)))  short bf16x8;
typedef __attribute__((ext_vector_type(16))) float f32x16;

__device__ __forceinline__ unsigned short f2bf(float f) {   // RNE f32->bf16
    unsigned int b = __float_as_uint(f);
    b += 0x7FFFu + ((b >> 16) & 1u);
    return (unsigned short)(b >> 16);
}
__device__ __forceinline__ float bf2f(unsigned short h) {
    return __uint_as_float(((unsigned int)h) << 16);
}

// valid on thread 0 only (512-thread blocks)
__device__ __forceinline__ float block_sum(float v, float* red) {
    #pragma unroll
    for (int off = 32; off > 0; off >>= 1)
        v += __shfl_down(v, off, 64);
    const int wid = threadIdx.x >> 6;
    if ((threadIdx.x & 63) == 0) red[wid] = v;
    __syncthreads();
    float s = 0.0f;
    if (threadIdx.x == 0)
        #pragma unroll
        for (int w = 0; w < 8; ++w) s += red[w];
    return s;
}

// ---------------------------------------------------------------------------
// K1 blocks [0,640): chamfer. block = (bs, dir, 256 queries) vs all 2048 g,
// staged in TWO 1024-point halves (32 KB LDS -> 3 blocks/CU, 6 waves/SIMD).
// One mfma_f32_32x32x16_bf16 per (32q x 32g) tile (layout validated in R8):
//   k0-7  (lanes 0-31):  A=[phx,phy,phz,plx,ply,plz, 1, 0]
//                        B=[ghx,ghy,ghz,ghx,ghy,ghz, mh,ml]
//   k8-15 (lanes 32-63): A=[phx,phy,phz, 1, 0,0,0,0]
//                        B=[glx,gly,glz, m3,0,0,0,0]
// score = ph.gh + pl.gh + ph.gl + (mh+ml+m3) ~= p.g - 0.5|g|^2  (err ~1e-5)
// Blocks [640,656): temporal.  Block 656: kl.
// ---------------------------------------------------------------------------
__global__ __launch_bounds__(512, 6) void k1_kernel(
        const float* __restrict__ pred, const float* __restrict__ tgt,
        const float* __restrict__ prior_mean, const float* __restrict__ prior_lv,
        const float* __restrict__ post_mean,  const float* __restrict__ post_lv,
        float* __restrict__ ws) {
    __shared__ alignas(16) unsigned short bh[HT][32][8];  // 16 KB hi-pack
    __shared__ alignas(16) unsigned short bl[HT][32][8];  // 16 KB lo-pack
    __shared__ float sm[8][32];
    __shared__ float red[8];

    const int bid = blockIdx.x;
    const int tid = threadIdx.x;

    if (bid < CHAM_BLOCKS) {
        const int qg  = bid & (NQG - 1);
        const int dir = (bid >> 3) & 1;
        const int bs  = bid >> 4;                 // b*S + s  (0..39)
        const float* qb  = (dir ? tgt : pred) + (size_t)bs * N * 3;  // queries
        const float* dbp = (dir ? pred : tgt) + (size_t)bs * N * 3;  // database

        // ---- A-fragment: 32 query rows per wave, split-bf16, bias slot 1.0 ----
        const int lane = tid & 63, wid = tid >> 6;
        const int hi = lane >> 5, qr = lane & 31;
        const int q = qg * QBLK + wid * 32 + qr;
        const float qx = qb[3 * q + 0], qy = qb[3 * q + 1], qz = qb[3 * q + 2];
        const float pn = fmaf(qx, qx, fmaf(qy, qy, qz * qz));  // exact fp32 |p|^2
        const short ONE = (short)0x3F80;
        bf16x8 a;
        {
            const unsigned short hx = f2bf(qx), hy = f2bf(qy), hz = f2bf(qz);
            if (hi == 0) {
                a[0] = (short)hx; a[1] = (short)hy; a[2] = (short)hz;
                a[3] = (short)f2bf(qx - bf2f(hx));
                a[4] = (short)f2bf(qy - bf2f(hy));
                a[5] = (short)f2bf(qz - bf2f(hz));
                a[6] = ONE; a[7] = 0;
            } else {
                a[0] = (short)hx; a[1] = (short)hy; a[2] = (short)hz;
                a[3] = ONE; a[4] = 0; a[5] = 0; a[6] = 0; a[7] = 0;
            }
        }

        const f32x16 zero16 = (f32x16)0.0f;
        f32x16 rmax = (f32x16)(-1e30f);

        for (int h = 0; h < 2; ++h) {
            if (h) __syncthreads();   // all waves done with previous half
            // ---- stage 1024 db points as split-bf16 B-fragments ----
            #pragma unroll
            for (int j = 0; j < 2; ++j) {
                const int p  = tid + 512 * j;          // local 0..1023
                const int gp = h * HPTS + p;
                const float x = dbp[3 * gp + 0];
                const float y = dbp[3 * gp + 1];
                const float z = dbp[3 * gp + 2];
                const unsigned short hx = f2bf(x), hy = f2bf(y), hz = f2bf(z);
                const unsigned short lx = f2bf(x - bf2f(hx));
                const unsigned short ly = f2bf(y - bf2f(hy));
                const unsigned short lz = f2bf(z - bf2f(hz));
                const float m  = -0.5f * (x * x + y * y + z * z);
                const unsigned short mh = f2bf(m);
                const float m1 = m - bf2f(mh);
                const unsigned short ml = f2bf(m1);
                const unsigned short m3 = f2bf(m1 - bf2f(ml));
                bf16x8 gv, lv;
                gv[0] = (short)hx; gv[1] = (short)hy; gv[2] = (short)hz;
                gv[3] = (short)hx; gv[4] = (short)hy; gv[5] = (short)hz;
                gv[6] = (short)mh; gv[7] = (short)ml;
                lv[0] = (short)lx; lv[1] = (short)ly; lv[2] = (short)lz;
                lv[3] = (short)m3; lv[4] = 0; lv[5] = 0; lv[6] = 0; lv[7] = 0;
                *(bf16x8*)&bh[p >> 5][p & 31][0] = gv;
                *(bf16x8*)&bl[p >> 5][p & 31][0] = lv;
            }
            __syncthreads();

            // ---- 32 tiles this half, paired; 1 MFMA per 1024 scores ----
            const char* bbase = (hi ? (const char*)bl : (const char*)bh)
                              + (size_t)qr * 16;
            #pragma unroll 2
            for (int tp = 0; tp < HT / 2; ++tp) {
                const bf16x8 b0 = *(const bf16x8*)(bbase + (size_t)(2 * tp + 0) * 512);
                const bf16x8 b1 = *(const bf16x8*)(bbase + (size_t)(2 * tp + 1) * 512);
                const f32x16 c0 = __builtin_amdgcn_mfma_f32_32x32x16_bf16(a, b0, zero16, 0, 0, 0);
                const f32x16 c1 = __builtin_amdgcn_mfma_f32_32x32x16_bf16(a, b1, zero16, 0, 0, 0);
                #pragma unroll
                for (int j = 0; j < 16; ++j)
                    rmax[j] = fmaxf(fmaxf(rmax[j], c0[j]), c1[j]);   // v_max3_f32
            }
        }

        // ---- butterfly max over 32 g-columns (C: col=lane&31,
        //      row=(j&3)+8*(j>>2)+4*(lane>>5), verified m74/m101) ----
        #pragma unroll
        for (int j = 0; j < 16; ++j) {
            float v = rmax[j];
            v = fmaxf(v, __shfl_xor(v, 1, 64));
            v = fmaxf(v, __shfl_xor(v, 2, 64));
            v = fmaxf(v, __shfl_xor(v, 4, 64));
            v = fmaxf(v, __shfl_xor(v, 8, 64));
            v = fmaxf(v, __shfl_xor(v, 16, 64));
            rmax[j] = v;
        }
        if (qr == 0) {   // lanes 0 and 32: 16 rows each
            #pragma unroll
            for (int j = 0; j < 16; ++j)
                sm[wid][(j & 3) + 8 * (j >> 2) + 4 * hi] = rmax[j];
        }
        __syncthreads();

        // ---- d = sqrt(|p|^2 - 2*smax), per-block sum ----
        float d = 0.0f;
        if (lane < 32) {
            const float s = sm[wid][qr];
            d = sqrtf(fmaxf(pn - 2.0f * s, 0.0f));
        }
        const float tot = block_sum(d, red);
        if (tid == 0) ws[WS_CHSUM + bid] = tot;
    } else if (bid < CHAM_BLOCKS + TEMP_BLOCKS) {
        // temporal: sum ||pred[:,s+1]-pred[:,s]||
        const int tb = bid - CHAM_BLOCKS;
        float s = 0.0f;
        for (int it = 0; it < TEMP_PER_BLOCK / THREADS; ++it) {
            const int i = tb * TEMP_PER_BLOCK + it * THREADS + tid;
            const int b = i / ((S - 1) * N);
            const int rr = i % ((S - 1) * N);
            const float* p0 = pred + (size_t)(b * S * N + rr) * 3;
            const float* p1 = p0 + (size_t)N * 3;
            const float dx = p1[0] - p0[0];
            const float dy = p1[1] - p0[1];
            const float dz = p1[2] - p0[2];
            s += sqrtf(dx * dx + dy * dy + dz * dz);
        }
        const float tot = block_sum(s, red);
        if (tid == 0) ws[WS_TPART + tb] = tot;
    } else {
        // kl term sum
        float s = 0.0f;
        for (int it = 0; it < KL_ELEMS / THREADS; ++it) {
            const int i = it * THREADS + tid;
            const float aa = prior_lv[i];
            const float bb = post_lv[i];
            const float dm = post_mean[i] - prior_mean[i];
            s += aa - bb + (expf(bb) + dm * dm) * expf(-aa) - 1.0f;
        }
        const float tot = block_sum(s, red);
        if (tid == 0) ws[WS_KL] = tot;
    }
}

// ---------------------------------------------------------------------------
// K3: final combine
// ---------------------------------------------------------------------------
__global__ __launch_bounds__(512) void k3_kernel(const float* __restrict__ ws,
                                                 float* __restrict__ out) {
    __shared__ float red[8];
    float s = 0.0f;
    for (int i = threadIdx.x; i < CHAM_BLOCKS; i += THREADS)
        s += ws[WS_CHSUM + i];
    const float tot = block_sum(s, red);
    if (threadIdx.x == 0) {
        float tsum = 0.0f;
        for (int i = 0; i < TEMP_BLOCKS; ++i) tsum += ws[WS_TPART + i];
        const float recon    = tot / (float)(B * S * N);
        const float kl       = 0.5f * ws[WS_KL] / (float)(B * S);
        const float temporal = tsum / (float)TEMP_ELEMS;
        out[0] = recon + kl + 0.1f * temporal;
        out[1] = recon;
        out[2] = kl;
        out[3] = temporal;
        out[4] = 0.0f;
    }
}

extern "C" void kernel_launch(void* const* d_in, const int* in_sizes, int n_in,
                              void* d_out, int out_size, void* d_ws, size_t ws_size,
                              hipStream_t stream) {
    const float* pred = (const float*)d_in[0];
    const float* tgt  = (const float*)d_in[1];
    const float* pm   = (const float*)d_in[2];
    const float* plv  = (const float*)d_in[3];
    const float* qm   = (const float*)d_in[4];
    const float* qlv  = (const float*)d_in[5];
    float* out = (float*)d_out;
    float* ws  = (float*)d_ws;

    k1_kernel<<<K1_GRID, THREADS, 0, stream>>>(pred, tgt, pm, plv, qm, qlv, ws);
    k3_kernel<<<1, THREADS, 0, stream>>>(ws, out);
}